// Round 12
// baseline (241.448 us; speedup 1.0000x reference)
//
#include <hip/hip_runtime.h>
#include <hip/hip_bf16.h>
#include <math.h>

#define NEG_SLOPE 0.2f
#define BUCK_BITS 5
#define BUCK_NODES 32             // dst nodes per fine bucket (aggregate block)

#define CBITS 8
#define CNODES 256                // dst nodes per coarse bucket
#define CAPC 4672                 // coarse capacity (mean 4096 + 9 sigma)
#define NC_MAX 400
#define NBIN 256                  // bin-role blocks inside fused kernel
#define NGEMM 256                 // gemm-role blocks

typedef __bf16 bf16x8 __attribute__((ext_vector_type(8)));
typedef __bf16 bf16x4 __attribute__((ext_vector_type(4)));
typedef float  f32x4  __attribute__((ext_vector_type(4)));

// ---------------- K0: prep = pack W (bf16 fragment order) + zero ccur --------
// B[k][n] with n = nt*16 + (lane&15), k = kt*32 + (lane>>4)*8 + j
__global__ void prep(const float* __restrict__ W, __bf16* __restrict__ Whi,
                     unsigned int* __restrict__ ccur) {
    int idx = blockIdx.x * blockDim.x + threadIdx.x;
    if (idx < NC_MAX) ccur[idx] = 0u;
    if (idx >= 8192) return;
    int j = idx & 7, lane = (idx >> 3) & 63, nt = (idx >> 9) & 1, kt = idx >> 10;
    int q = lane >> 4, c = lane & 15;
    int k = kt * 32 + q * 8 + j;
    int n = nt * 16 + c;
    Whi[idx] = (__bf16)W[k * 32 + n];
}

// ---------------- K1: FUSED gemm_h + coarse binning (byte-identical to r9) ---
// r9 measured-best (59.7 us); r11 depth-4 was neutral -> keep depth-2.
// gemm role: global_load_lds DMA staging, per-wave 2x4KB double buffer,
//   s_waitcnt vmcnt(4) counted (never 0) + sched_barrier(0) (rule 18); LDS
//   reads conflict-mitigated by XOR swizzle applied on the per-lane GLOBAL
//   source (LDS dest stays linear). feat = Ah+Al split-bf16 MFMA (Ah@Bl
//   dropped, err ~2e-3); h stored bf16; el/er from f32 accumulators.
// bin role: int4-vectorized hist+scan+scatter, 64 B contiguous chunks per
//   (block,bucket) -> no cross-XCD sub-line amp. Record: (dst&255)<<17 | src.
__global__ __launch_bounds__(256) void gemm_bin(const float* __restrict__ feat,
                                                const __bf16* __restrict__ Whi,
                                                const float* __restrict__ attn_l,
                                                const float* __restrict__ attn_r,
                                                const int* __restrict__ src,
                                                const int* __restrict__ dst,
                                                __bf16* __restrict__ hb,
                                                float* __restrict__ el,
                                                float* __restrict__ er,
                                                unsigned int* __restrict__ ccur,
                                                unsigned int* __restrict__ cbin,
                                                int N, int Ntiles, int E, int NC) {
    union SM {
        struct { bf16x8 whi[1024]; float stage[4][2][1024]; } g;  // 16+32 KB
        struct { unsigned int hist[NC_MAX]; unsigned int cbase[NC_MAX]; } b;
    };
    __shared__ SM sm;

    int bid = blockIdx.x;
    int tid = threadIdx.x;
    int role = bid & 1, gid = bid >> 1;

    if (role == 1) {
        // ---------------- binning path (int4-vectorized, r7) ----------------
        unsigned int* hist  = sm.b.hist;
        unsigned int* cbase = sm.b.cbase;
        int batch = (((E + NBIN - 1) / NBIN) + 3) & ~3;   // multiple of 4
        int b0 = gid * batch;
        int b1 = min(b0 + batch, E);
        int nv = (b0 < b1) ? ((b1 - b0) >> 2) : 0;        // E%4==0 -> exact
        const int4* d4 = (const int4*)(dst + b0);
        const int4* s4 = (const int4*)(src + b0);
        for (int i = tid; i < NC; i += 256) hist[i] = 0;
        __syncthreads();
        for (int i = tid; i < nv; i += 256) {
            int4 dd = d4[i];
#pragma unroll
            for (int j = 0; j < 4; j++)
                atomicAdd(&hist[((unsigned)(&dd.x)[j]) >> CBITS], 1u);
        }
        __syncthreads();
        for (int i = tid; i < NC; i += 256) {
            unsigned c = hist[i];
            cbase[i] = c ? atomicAdd(&ccur[i], c) : 0u;
            hist[i] = 0;  // reuse as local rank cursor
        }
        __syncthreads();
        for (int i = tid; i < nv; i += 256) {
            int4 dd = d4[i];
            int4 ss = s4[i];
#pragma unroll
            for (int j = 0; j < 4; j++) {
                int d = (&dd.x)[j];
                int s = (&ss.x)[j];
                unsigned cb = ((unsigned)d) >> CBITS;
                unsigned r = atomicAdd(&hist[cb], 1u);
                unsigned pos = cbase[cb] + r;
                if (pos < CAPC)  // never true for this input; guards corruption
                    cbin[(size_t)cb * CAPC + pos] =
                        ((unsigned)(d & (CNODES - 1)) << 17) | (unsigned)s;
            }
        }
        return;
    }

    // ---------------- gemm path ----------------
    for (int i = tid; i < 1024; i += 256) sm.g.whi[i] = ((const bf16x8*)Whi)[i];
    __syncthreads();

    int wv   = tid >> 6;
    int lane = tid & 63;
    int cc = lane & 15, qd = lane >> 4;
    int swz = (cc & 7) << 4;

    int gw = gid * 4 + wv;                // global wave id, 0..1023
    int nt = (Ntiles - gw + 1023) >> 10;  // tiles for this wave (>=1 here)
    int Q  = 4 * nt;                      // quarters

    float* buf0 = &sm.g.stage[wv][0][0];
    float* buf1 = &sm.g.stage[wv][1][0];

    auto stage_q = [&](int q) {
        int qc = q < Q ? q : Q - 1;
        int t  = gw + ((qc >> 2) << 10);
        int kq = qc & 3;
        float* lb = (q & 1) ? buf1 : buf0;
#pragma unroll
        for (int j = 0; j < 4; j++) {
            int r = 4 * j + (lane >> 4);
            int grow = t * 16 + r;
            if (grow >= N) grow = N - 1;  // defensive clamp
            int seg = ((lane & 15) * 16) ^ ((r & 7) << 4);
            const char* sp = (const char*)feat +
                             ((size_t)grow * 256 + kq * 64) * 4 + seg;
            __builtin_amdgcn_global_load_lds(
                (const __attribute__((address_space(1))) void*)sp,
                (__attribute__((address_space(3))) void*)(lb + j * 256),
                16, 0, 0);
        }
    };

    stage_q(0);
    stage_q(1);

    float alc  = attn_l[cc],      arc  = attn_r[cc];
    float alc2 = attn_l[cc + 16], arc2 = attn_r[cc + 16];

    f32x4 acc0 = {0.f, 0.f, 0.f, 0.f};
    f32x4 acc1 = {0.f, 0.f, 0.f, 0.f};

    for (int i = 0; i < nt; i++) {
#pragma unroll
        for (int kq2 = 0; kq2 < 4; kq2++) {
            int q = i * 4 + kq2;
            asm volatile("s_waitcnt vmcnt(4)" ::: "memory");
            __builtin_amdgcn_sched_barrier(0);
            const char* lb = (const char*)((q & 1) ? buf1 : buf0);
#pragma unroll
            for (int jj = 0; jj < 2; jj++) {
                int kt = kq2 * 2 + jj;
                int so = jj * 128 + qd * 32;
                f32x4 a0 = *(const f32x4*)(lb + cc * 256 + ((so)      ^ swz));
                f32x4 a1 = *(const f32x4*)(lb + cc * 256 + ((so + 16) ^ swz));
                bf16x8 ah, al;
#pragma unroll
                for (int j = 0; j < 4; j++) {
                    __bf16 h0 = (__bf16)a0[j];
                    __bf16 h1 = (__bf16)a1[j];
                    ah[j]     = h0;
                    ah[j + 4] = h1;
                    al[j]     = (__bf16)(a0[j] - (float)h0);
                    al[j + 4] = (__bf16)(a1[j] - (float)h1);
                }
                bf16x8 bh0 = sm.g.whi[(kt * 2 + 0) * 64 + lane];
                bf16x8 bh1 = sm.g.whi[(kt * 2 + 1) * 64 + lane];
                acc0 = __builtin_amdgcn_mfma_f32_16x16x32_bf16(ah, bh0, acc0, 0, 0, 0);
                acc0 = __builtin_amdgcn_mfma_f32_16x16x32_bf16(al, bh0, acc0, 0, 0, 0);
                acc1 = __builtin_amdgcn_mfma_f32_16x16x32_bf16(ah, bh1, acc1, 0, 0, 0);
                acc1 = __builtin_amdgcn_mfma_f32_16x16x32_bf16(al, bh1, acc1, 0, 0, 0);
            }
            if (kq2 == 3) {
                // epilogue BEFORE staging, so vmcnt(4) never waits on a
                // just-issued stage. C/D layout: col=lane&15, row=q*4+reg.
                int t = gw + (i << 10);
#pragma unroll
                for (int r = 0; r < 4; r++) {
                    int m = t * 16 + qd * 4 + r;
                    if (m < N) {
                        hb[(size_t)m * 32 + cc]      = (__bf16)acc0[r];
                        hb[(size_t)m * 32 + 16 + cc] = (__bf16)acc1[r];
                    }
                    float pl = acc0[r] * alc + acc1[r] * alc2;
                    float pr = acc0[r] * arc + acc1[r] * arc2;
#pragma unroll
                    for (int off = 8; off >= 1; off >>= 1) {
                        pl += __shfl_xor(pl, off);
                        pr += __shfl_xor(pr, off);
                    }
                    if (cc == 0 && m < N) { el[m] = pl; er[m] = pr; }
                }
                acc0 = (f32x4){0.f, 0.f, 0.f, 0.f};
                acc1 = (f32x4){0.f, 0.f, 0.f, 0.f};
            }
            __builtin_amdgcn_sched_barrier(0);  // keep stage after all reads
            stage_q(q + 2);
        }
    }
}

// ---------------- K2: sortw = per-NODE sort + softmax weights + denominators -
// One 512-thread block per coarse bucket (391). Replaces refine AND hoists
// aggregate's entire serial phase (hist/scan/scatter/expf) out of the 3125
// fine blocks into 391 balanced blocks that each scan cbin twice (2nd L2-hot):
//   pass 1: per-node (256-bin) LDS histogram
//   scan:   256-entry exclusive prefix (4-wave shfl + wave-sum fixup)
//   pass 2: w = exp(leaky(el[s]+er[d])), scatter (src,w) uint2 into fbin
//           sorted by node; LDS atomicAdd denominators
// Outputs: fbin (node-sorted records), noff[cb*257+i] per-node start offsets
// (+[256]=end), deng[N] denominators. Block writes one contiguous ~37 KB fbin
// region -> chunked, no cross-XCD amp (r3 lesson).
__global__ __launch_bounds__(512) void sortw(const unsigned int* __restrict__ ccur,
                                             const unsigned int* __restrict__ cbin,
                                             const float* __restrict__ el,
                                             const float* __restrict__ er,
                                             uint2* __restrict__ fbin,
                                             int* __restrict__ noff,
                                             float* __restrict__ deng,
                                             int N, int NC) {
    __shared__ unsigned int hist[CNODES];
    __shared__ float        denL[CNODES];
    __shared__ float        er_l[CNODES];
    __shared__ int          wsum[5];

    int cb = blockIdx.x;
    int base = cb << CBITS;
    int tid = threadIdx.x;
    int lane = tid & 63, wvv = tid >> 6;

    int cnt = (int)min(ccur[cb], (unsigned)CAPC);
    const unsigned int* cp = cbin + (size_t)cb * CAPC;

    if (tid < CNODES) {
        hist[tid] = 0;
        denL[tid] = 0.f;
        er_l[tid] = (base + tid < N) ? er[base + tid] : 0.f;
    }
    __syncthreads();

    // pass 1: per-node histogram
    for (int i = tid; i < cnt; i += 512)
        atomicAdd(&hist[(cp[i] >> 17) & (CNODES - 1)], 1u);
    __syncthreads();

    // 256-entry exclusive scan (waves 0-3)
    int v = 0, orig = 0;
    if (tid < CNODES) {
        v = (int)hist[tid];
        orig = v;
#pragma unroll
        for (int off = 1; off < 64; off <<= 1) {
            int x = __shfl_up(v, off, 64);
            if (lane >= off) v += x;
        }
        if (lane == 63) wsum[wvv] = v;
    }
    __syncthreads();
    if (tid == 0) {
        int s = 0;
#pragma unroll
        for (int w = 0; w < 4; w++) { int t = wsum[w]; wsum[w] = s; s += t; }
        wsum[4] = s;
    }
    __syncthreads();
    if (tid < CNODES) {
        int off = v - orig + wsum[wvv];
        noff[cb * 257 + tid] = cb * CAPC + off;
        hist[tid] = (unsigned)off;     // scatter cursor (bucket-local)
        if (tid == 0) noff[cb * 257 + CNODES] = cb * CAPC + cnt;
    }
    __syncthreads();

    // pass 2: weight + node-sorted scatter + denominators (cbin re-read L2-hot)
    for (int i = tid; i < cnt; i += 512) {
        unsigned r = cp[i];
        int s  = (int)(r & 0x1FFFFu);
        int ln = (int)((r >> 17) & (CNODES - 1));
        float e = el[s] + er_l[ln];
        e = (e > 0.f) ? e : NEG_SLOPE * e;
        float w = __expf(e);
        unsigned pos = atomicAdd(&hist[ln], 1u);
        if (pos < (unsigned)CAPC) {  // always true by construction; guards
            fbin[(size_t)cb * CAPC + pos] =
                make_uint2((unsigned)s, __float_as_uint(w));
            atomicAdd(&denL[ln], w);
        }
    }
    __syncthreads();
    if (tid < CNODES && base + tid < N) deng[base + tid] = denL[tid];
}

// ---------------- K3: pure gather (no LDS, no barriers, no atomics) ----------
// 3125 blocks x 256 threads (balanced — r10 lesson). Per wave per node: read
// per-node extent from noff, denominator from deng, stream contiguous (src,w)
// records (64 B/line per wave-iter), oct-lane bf16x4 h-gather (1 line/edge,
// 8 edges in flight/wave), 3-stage reduce, scale+bias, write.
__global__ __launch_bounds__(256) void aggregate(const int* __restrict__ noff,
                                                 const float* __restrict__ deng,
                                                 const uint2* __restrict__ fbin,
                                                 const __bf16* __restrict__ hb,
                                                 const float* __restrict__ bias,
                                                 float* __restrict__ out, int N) {
    int buck = blockIdx.x;
    int cb = buck >> 3;
    int fo = (buck & 7) << 5;            // fine offset within coarse: 0..224
    int base = buck << BUCK_BITS;
    int nn = min(BUCK_NODES, N - base);
    int tid = threadIdx.x;
    int lane = tid & 63, wv = tid >> 6;
    int oct = lane >> 3, t = lane & 7;

    const int* np = noff + cb * 257 + fo;
    f32x4 b4 = *(const f32x4*)&bias[t * 4];

    for (int n = wv; n < nn; n += 4) {
        int s0 = np[n], s1 = np[n + 1];
        float sm = deng[base + n];
        f32x4 acc = {0.f, 0.f, 0.f, 0.f};
#pragma unroll 2
        for (int j = s0 + oct; j < s1; j += 8) {
            uint2 rw = fbin[j];
            float w = __uint_as_float(rw.y);
            bf16x4 hv = *(const bf16x4*)&hb[(size_t)rw.x * 32 + t * 4];
            acc[0] += w * (float)hv[0];
            acc[1] += w * (float)hv[1];
            acc[2] += w * (float)hv[2];
            acc[3] += w * (float)hv[3];
        }
#pragma unroll
        for (int off = 8; off <= 32; off <<= 1) {
            acc[0] += __shfl_xor(acc[0], off);
            acc[1] += __shfl_xor(acc[1], off);
            acc[2] += __shfl_xor(acc[2], off);
            acc[3] += __shfl_xor(acc[3], off);
        }
        if (lane < 8) {
            f32x4 o;
            if (sm > 0.f) {
                float inv = 1.f / sm;
                o[0] = acc[0] * inv + b4[0];
                o[1] = acc[1] * inv + b4[1];
                o[2] = acc[2] * inv + b4[2];
                o[3] = acc[3] * inv + b4[3];
            } else {
                o = b4;  // isolated node
            }
            *(f32x4*)&out[(size_t)(base + n) * 32 + t * 4] = o;
        }
    }
}

// ---------------- host launch -----------------------------------------------
static inline size_t align256(size_t x) { return (x + 255) & ~(size_t)255; }

extern "C" void kernel_launch(void* const* d_in, const int* in_sizes, int n_in,
                              void* d_out, int out_size, void* d_ws, size_t ws_size,
                              hipStream_t stream) {
    const float* feat   = (const float*)d_in[0];
    const float* W      = (const float*)d_in[1];
    const float* attn_l = (const float*)d_in[2];
    const float* attn_r = (const float*)d_in[3];
    const float* bias   = (const float*)d_in[4];
    const int* src = (const int*)d_in[5];
    const int* dst = (const int*)d_in[6];
    float* out = (float*)d_out;

    const int IN = 256;
    int N = in_sizes[0] / IN;   // 100000
    int E = in_sizes[5];        // 1600000
    (void)n_in; (void)out_size; (void)ws_size;

    int Ntiles = (N + 15) / 16;                    // 6250
    int NBUK = (N + BUCK_NODES - 1) >> BUCK_BITS;  // 3125 fine buckets
    int NC   = (N + CNODES - 1) >> CBITS;          // 391  (<= NC_MAX)

    char* p = (char*)d_ws;
    __bf16* hb     = (__bf16*)p; p += align256((size_t)N * 32 * 2);
    float* el      = (float*)p; p += align256((size_t)N * 4);
    float* er      = (float*)p; p += align256((size_t)N * 4);
    float* deng    = (float*)p; p += align256((size_t)N * 4);
    unsigned int* ccur = (unsigned int*)p; p += align256((size_t)NC_MAX * 4);
    unsigned int* cbin = (unsigned int*)p; p += align256((size_t)NC * CAPC * 4);
    uint2* fbin    = (uint2*)p; p += align256((size_t)NC * CAPC * 8);
    int* noff      = (int*)p;   p += align256((size_t)NC_MAX * 257 * 4);
    __bf16* Whi    = (__bf16*)p; p += align256((size_t)8192 * 2);

    prep<<<33, 256, 0, stream>>>(W, Whi, ccur);
    gemm_bin<<<NGEMM + NBIN, 256, 0, stream>>>(feat, Whi, attn_l, attn_r,
                                               src, dst, hb, el, er, ccur, cbin,
                                               N, Ntiles, E, NC);
    sortw<<<NC, 512, 0, stream>>>(ccur, cbin, el, er, fbin, noff, deng, N, NC);
    aggregate<<<NBUK, 256, 0, stream>>>(noff, deng, fbin, hb, bias, out, N);
}